// Round 4
// baseline (294.880 us; speedup 1.0000x reference)
//
#include <hip/hip_runtime.h>
#include <hip/hip_bf16.h>
#include <stdint.h>

typedef __attribute__((ext_vector_type(8))) short short8;
typedef __attribute__((ext_vector_type(4))) float f32x4;

#define XPP_BYTES 66355200ull   // 8rh*8cw*2b*15rho*15cwo*18d*64ci*2B
#define XPP_SLACK 65536ull      // staging over-read pad
#define WPP_BYTES 14155776ull   // 64hw*27tap*64co*64ci*2B

__device__ __forceinline__ void gl2lds16(const void* g, void* l) {
    __builtin_amdgcn_global_load_lds(
        (const __attribute__((address_space(1))) unsigned int*)g,
        (__attribute__((address_space(3))) unsigned int*)l, 16, 0, 0);
}

// ---------------- bzero: zero only X''' halo (rho=0 | cwo=0 | d in {0,17}) --
// X''' unit map (uint4 = 8 elems): per (s=rh*8+cw, b) slab = 32400 u4;
// rho stride 2160 u4; cwo stride 144 u4; d stride 8 u4.
__global__ __launch_bounds__(256)
void bzero(uint4* __restrict__ xpp) {
    const uint4 z = {0u, 0u, 0u, 0u};
    const int total = 935936;  // 276480 + 258048 + 401408
    for (int idx = blockIdx.x * 256 + threadIdx.x; idx < total;
         idx += gridDim.x * 256) {
        int u;
        if (idx < 276480) {                       // rho = 0 plane (contig 2160)
            int slab = idx / 2160, off = idx % 2160;
            u = slab * 32400 + off;
        } else if (idx < 534528) {                // cwo = 0, rho 1..14
            int k = idx - 276480;
            int run = k / 144, off = k % 144;
            int slab = run / 14, rho = run % 14 + 1;
            u = slab * 32400 + rho * 2160 + off;
        } else {                                  // d in {0,17}, rho,cwo 1..14
            int k = idx - 534528;
            int run = k / 8, off = k % 8;
            int slab = run / 392, r2 = run % 392;
            int rho = r2 / 28 + 1, r3 = r2 % 28;
            int cwo = r3 / 2 + 1, d = (r3 & 1) * 17;
            u = slab * 32400 + rho * 2160 + cwo * 144 + d * 8 + off;
        }
        xpp[u] = z;
    }
}

// ---------------- T1: X (f32) -> X''' (bf16, space-to-depth, d-innermost) --
// X'''[rh][cw][b][rho(15)][cwo(15)][d(18)][ci(64)]; src depth d at d+1,
// rho/cwo at +1; halo pre-zeroed by bzero.
__global__ __launch_bounds__(512)
void xform_x(const float* __restrict__ xin, __hip_bfloat16* __restrict__ xpp) {
    extern __shared__ __hip_bfloat16 Xl[];  // [r8][c112][ci64] swizzled
    const int bid = blockIdx.x;
    const int rho = bid % 14, d = (bid / 14) % 16, b = bid / 224;
    const int tid = threadIdx.x;
    for (int f = tid; f < 64 * 8 * 28; f += 512) {
        int ci = f / 224, rem = f % 224;
        int r = rem / 28, c4 = (rem % 28) * 4;
        const float4 v = *(const float4*)&xin[
            ((((size_t)b * 64 + ci) * 16 + d) * 112 + (rho * 8 + r)) * 112 + c4];
        const float vv[4] = {v.x, v.y, v.z, v.w};
#pragma unroll
        for (int u = 0; u < 4; ++u) {
            int c = c4 + u;
            Xl[(r * 112 + c) * 64 + (ci ^ ((c & 7) << 3))] = __float2bfloat16(vv[u]);
        }
    }
    __syncthreads();
    for (int f = tid; f < 896 * 8; f += 512) {
        int pos = f >> 3, j = f & 7;
        int r = pos / 112, c = pos % 112;
        int cw = c & 7, cwo = c >> 3;
        uint4 v = *(const uint4*)&Xl[pos * 64 + ((j * 8) ^ ((c & 7) << 3))];
        size_t dst = (((((size_t)(r * 8 + cw) * 2 + b) * 15 + (rho + 1)) * 15
                       + (cwo + 1)) * 18 + (d + 1)) * 64 + j * 8;
        *(uint4*)(xpp + dst) = v;
    }
}

// ---------------- T2: W (f32) -> W''[hw][tap][co][ci] (bf16) ---------------
__global__ __launch_bounds__(256)
void xform_w(const float* __restrict__ wt, __hip_bfloat16* __restrict__ wpp) {
    __shared__ __hip_bfloat16 lw[8 * 27 * 72];  // [co8][k27][ci64 pad72]
    const int hw = blockIdx.x >> 3, cc = blockIdx.x & 7;
    for (int f = threadIdx.x; f < 8 * 64 * 27; f += 256) {
        int k = f % 27, ci = (f / 27) % 64, co = f / (27 * 64);
        float v = wt[(size_t)hw * 110592 + (size_t)(cc * 8 + co) * 1728 + ci * 27 + k];
        lw[(co * 27 + k) * 72 + ci] = __float2bfloat16(v);
    }
    __syncthreads();
    for (int f = threadIdx.x; f < 27 * 8 * 8; f += 256) {
        int cic = f % 8, co = (f / 8) % 8, k = f / 64;
        uint4 v = *(const uint4*)&lw[(co * 27 + k) * 72 + cic * 8];
        size_t dst = (((size_t)hw * 27 + k) * 64 + (cc * 8 + co)) * 64 + cic * 8;
        *(uint4*)(wpp + dst) = v;
    }
}

// ---------------- GEMM: per (h,w,b,mc): [224m x 64co], m=(wo,t) ------------
// 9 rounds of (kh,kw); each round stages one 18-d A-line (32.25 KB) shared by
// the 3 kd taps; B fragments loaded global->reg (L2-resident, h-pinned XCD).
__global__ __launch_bounds__(256, 2)
void patgemm(const __hip_bfloat16* __restrict__ xpp,
             const __hip_bfloat16* __restrict__ wpp,
             const float* __restrict__ bs,
             float* __restrict__ out) {
    extern __shared__ char smem[];  // 2 x 32768 B A-line buffers
    const int bid = blockIdx.x;
    const int h = bid & 7, k = bid >> 3;
    const int w = k & 7, b = (k >> 3) & 1, mc = k >> 4;
    const int hw = h * 8 + w;
    const int tid = threadIdx.x, wv = tid >> 6, lane = tid & 63;
    const int col = lane & 15, quad = lane >> 4;
    const int mg = wv >> 1, ng = wv & 1;

    // staging source offsets (line-relative, inverse-swizzled)
    uint32_t aoff[8];
#pragma unroll
    for (int i = 0; i < 8; ++i) {
        int slot = tid + i * 256;           // 0..2047 (2016 real + pad)
        int wo = slot / 144, rem = slot % 144;
        int rt = rem >> 3, ch = rem & 7;
        aoff[i] = (uint32_t)(wo * 2304 + rt * 128 + ((ch ^ (rt & 7)) << 4));
    }
    // fragment read offsets per (kd,ks): row = col+kd, chunk = ks*4+quad
    uint32_t rofs[3][2];
#pragma unroll
    for (int kd = 0; kd < 3; ++kd)
#pragma unroll
        for (int ks = 0; ks < 2; ++ks)
            rofs[kd][ks] = (uint32_t)((col + kd) * 128
                + (((ks * 4 + quad) ^ ((col + kd) & 7)) << 4));
    const uint32_t bofs = (uint32_t)(col * 128 + quad * 16);

    f32x4 acc[7][2];
#pragma unroll
    for (int j = 0; j < 7; ++j)
#pragma unroll
        for (int n = 0; n < 2; ++n) acc[j][n] = (f32x4){0.f, 0.f, 0.f, 0.f};

    const char* wbase = (const char*)wpp + (size_t)hw * 27 * 8192;

    auto STAGE = [&](int bi, int rr) {
        const int kh = rr / 3, kw = rr % 3;
        const int r0 = h + kh - 7, c0 = w + kw - 7;
        const char* ap = (const char*)xpp +
            (size_t)(((((r0 & 7) * 8 + (c0 & 7)) * 2 + b) * 15
                      + ((r0 >> 3) + 1 + mc)) * 15 + ((c0 >> 3) + 1)) * 2304;
        char* Ad = smem + bi * 32768;
#pragma unroll
        for (int i = 0; i < 8; ++i)
            gl2lds16(ap + aoff[i], Ad + (uint32_t)(tid + i * 256) * 16);
    };

    STAGE(0, 0);
    __syncthreads();

#pragma unroll 1
    for (int rr = 0; rr < 9; ++rr) {
        const int cur = rr & 1;
        // B fragments for this round's 3 taps (tap = kd*9+rr), ISSUED FIRST
        short8 bfr[12];
        const char* bp = wbase + (size_t)rr * 8192;
#pragma unroll
        for (int kd = 0; kd < 3; ++kd)
#pragma unroll
            for (int ks = 0; ks < 2; ++ks)
#pragma unroll
                for (int n = 0; n < 2; ++n)
                    bfr[kd * 4 + ks * 2 + n] = *(const short8*)(
                        bp + kd * 73728 + (ng * 2 + n) * 2048 + ks * 64 + bofs);
        __builtin_amdgcn_sched_barrier(0);  // keep B issue before A-DMA
        if (rr < 8) STAGE(cur ^ 1, rr + 1);
        const char* Ab = smem + cur * 32768;
#pragma unroll
        for (int kd = 0; kd < 3; ++kd) {
#pragma unroll
            for (int ks = 0; ks < 2; ++ks) {
                short8 af[7];
#pragma unroll
                for (int j = 0; j < 7; ++j)
                    af[j] = *(const short8*)(Ab + (mg * 7 + j) * 2304 + rofs[kd][ks]);
                __builtin_amdgcn_s_setprio(1);
#pragma unroll
                for (int j = 0; j < 7; ++j)
#pragma unroll
                    for (int n = 0; n < 2; ++n)
                        acc[j][n] = __builtin_amdgcn_mfma_f32_16x16x32_bf16(
                            af[j], bfr[kd * 4 + ks * 2 + n], acc[j][n], 0, 0, 0);
                __builtin_amdgcn_s_setprio(0);
            }
        }
        __syncthreads();  // vmcnt(0) drain: next A-line landed (issued ~4K cyc ago)
    }

    // epilogue: D col=lane&15 (co-within-tile / t source), row=quad*4+jj (t)
    const float* bsl = bs + hw * 64;
    const int y = 8 * mc + h;
#pragma unroll
    for (int j = 0; j < 7; ++j) {
        const int wo = mg * 7 + j;
        const int x = 8 * wo + w;
#pragma unroll
        for (int n = 0; n < 2; ++n) {
            const int co = (ng * 2 + n) * 16 + col;
            const float bv = bsl[co];
#pragma unroll
            for (int jj = 0; jj < 4; ++jj) {
                const int t = quad * 4 + jj;
                out[((((size_t)b * 64 + co) * 16 + t) * 112 + y) * 112 + x]
                    = acc[j][n][jj] + bv;
            }
        }
    }
}

// ---------------- fallback: round-1 fp32 kernel (used if ws too small) -----
#define XL_ROWSTRIDE 116
#define WL_WSTRIDE (17*27)

__global__ __launch_bounds__(256, 3)
void patconv3d_fp32(const float* __restrict__ xin,
                    const float* __restrict__ wt,
                    const float* __restrict__ bs,
                    float* __restrict__ out) {
    __shared__ float Xl[3*3*7*XL_ROWSTRIDE];
    __shared__ float Wl[8*WL_WSTRIDE];
    const int bid = blockIdx.x;
    const int ct = bid & 3, hb = (bid >> 2) & 1, h = (bid >> 3) & 7;
    const int t = (bid >> 6) & 15, b = (bid >> 10) & 1;
    const int tid = threadIdx.x;
    const int xl = tid & 127, cg = tid >> 7;
    const int xr = (xl < 112) ? xl : 111;
    const int wq = xl & 7;
    float acc[8][7];
#pragma unroll
    for (int c = 0; c < 8; ++c)
#pragma unroll
        for (int ho = 0; ho < 7; ++ho) acc[c][ho] = 0.f;
    for (int ci = 0; ci < 64; ++ci) {
        __syncthreads();
        for (int idx = tid; idx < 3 * 3 * 7 * 114; idx += 256) {
            int c = idx % 114, rest = idx / 114;
            int ho = rest % 7; rest /= 7;
            int kh = rest % 3, kd = rest / 3;
            int r = 8 * (hb * 7 + ho) + h + kh - 7;
            int d = t + kd - 1, colx = c - 7;
            float v = 0.f;
            if (r >= 0 && d >= 0 && d < 16 && colx >= 0)
                v = xin[(((size_t)(b * 64 + ci) * 16 + d) * 112 + r) * 112 + colx];
            Xl[((kd * 3 + kh) * 7 + ho) * XL_ROWSTRIDE + c] = v;
        }
        for (int idx = tid; idx < 8 * 16 * 27; idx += 256) {
            int k = idx % 27, rest = idx / 27;
            int co_l = rest % 16, wi = rest / 16;
            Wl[wi * WL_WSTRIDE + co_l * 27 + k] =
                wt[(((size_t)(h * 8 + wi) * 64 + (ct * 16 + co_l)) * 64 + ci) * 27 + k];
        }
        __syncthreads();
#pragma unroll
        for (int kd = 0; kd < 3; ++kd)
#pragma unroll
            for (int kh = 0; kh < 3; ++kh)
#pragma unroll
                for (int kw = 0; kw < 3; ++kw) {
                    const int k = (kd * 3 + kh) * 3 + kw;
                    float xv[7];
#pragma unroll
                    for (int ho = 0; ho < 7; ++ho)
                        xv[ho] = Xl[((kd * 3 + kh) * 7 + ho) * XL_ROWSTRIDE + xr + kw];
                    float wv[8];
#pragma unroll
                    for (int c = 0; c < 8; ++c)
                        wv[c] = Wl[wq * WL_WSTRIDE + (cg * 8 + c) * 27 + k];
#pragma unroll
                    for (int c = 0; c < 8; ++c)
#pragma unroll
                        for (int ho = 0; ho < 7; ++ho)
                            acc[c][ho] += wv[c] * xv[ho];
                }
    }
    if (xl < 112) {
#pragma unroll
        for (int c = 0; c < 8; ++c) {
            const int co = ct * 16 + cg * 8 + c;
            const float bv = bs[(h * 8 + wq) * 64 + co];
#pragma unroll
            for (int ho = 0; ho < 7; ++ho) {
                const int y = 8 * (hb * 7 + ho) + h;
                out[(((size_t)(b * 64 + co) * 16 + t) * 112 + y) * 112 + xl] = acc[c][ho] + bv;
            }
        }
    }
}

extern "C" void kernel_launch(void* const* d_in, const int* in_sizes, int n_in,
                              void* d_out, int out_size, void* d_ws, size_t ws_size,
                              hipStream_t stream) {
    const float* x  = (const float*)d_in[0];
    const float* wg = (const float*)d_in[1];
    const float* bi = (const float*)d_in[2];
    float* out = (float*)d_out;
    if (ws_size >= XPP_BYTES + XPP_SLACK + WPP_BYTES) {
        __hip_bfloat16* xpp = (__hip_bfloat16*)d_ws;
        __hip_bfloat16* wpp = (__hip_bfloat16*)((char*)d_ws + XPP_BYTES + XPP_SLACK);
        bzero<<<1024, 256, 0, stream>>>((uint4*)d_ws);
        xform_x<<<448, 512, 114688, stream>>>(x, xpp);
        xform_w<<<512, 256, 0, stream>>>(wg, wpp);
        patgemm<<<1792, 256, 65536, stream>>>(xpp, wpp, bi, out);
    } else {
        patconv3d_fp32<<<2048, 256, 0, stream>>>(x, wg, bi, out);
    }
}